// Round 6
// baseline (283.990 us; speedup 1.0000x reference)
//
#include <hip/hip_runtime.h>
#include <hip/hip_bf16.h>
#include <stdint.h>

typedef __attribute__((ext_vector_type(8))) _Float16 half8;
typedef __attribute__((ext_vector_type(4))) float f32x4;
typedef __attribute__((ext_vector_type(16))) float f32x16;

#define N_TOK  65536
#define DIM    256
#define NT     76          // 32-cluster tiles: 69 (L0) + 6 (L1) + 1 (L2)
#define TAU    0.12f

// padded layer map: L0 tiles [0,69) base 0 size 2197
//                   L1 tiles [69,75) base 2208 size 169
//                   L2 tile  75 base 2400 size 13

// workspace layout (bytes)
#define WS_FLAGCNT 0
#define WS_FLAGS   64
#define WS_NFLAGS  16384
#define WS_WNORM   (64 + WS_NFLAGS*4)        // 65600, 16B aligned
#define WS_WHFRAG  131072                    // fp16 hi frags: 76 tiles * 16KB

// -------- prep: pack W into 32x32x16 MFMA A-frag order (fp16 hi) + fp64 wnorm --
// frag slot q = s*64 + l  (s = K-step 0..15, l = lane): cluster = l&31,
// k = s*16 + (l>>5)*8 + j  (8 contiguous fp16 per lane)
__global__ void prep_kernel(const float* __restrict__ w0, const float* __restrict__ w1,
                            const float* __restrict__ w2, unsigned char* __restrict__ ws) {
  const int t = blockIdx.x;
  const int tid = threadIdx.x;           // 256 threads
  const float* wsrc; int basePad, csize;
  if (t < 69)      { wsrc = w0; basePad = 0;    csize = 2197; }
  else if (t < 75) { wsrc = w1; basePad = 2208; csize = 169;  }
  else             { wsrc = w2; basePad = 2400; csize = 13;   }
  half8* whf = (half8*)(ws + WS_WHFRAG);
#pragma unroll
  for (int r = 0; r < 4; ++r) {
    int q = r * 256 + tid;               // frag slot within tile
    int l = q & 63;
    int s = q >> 6;                      // 0..15
    int cit = l & 31;
    int k = s * 16 + (l >> 5) * 8;
    int cl = t * 32 + cit - basePad;
    float xs[8];
    if (cl < csize) {
      const float4* p = (const float4*)(wsrc + (size_t)cl * DIM + k);
      float4 a = p[0], b = p[1];
      xs[0]=a.x; xs[1]=a.y; xs[2]=a.z; xs[3]=a.w; xs[4]=b.x; xs[5]=b.y; xs[6]=b.z; xs[7]=b.w;
    } else {
#pragma unroll
      for (int j = 0; j < 8; ++j) xs[j] = 0.0f;
    }
    half8 h;
#pragma unroll
    for (int j = 0; j < 8; ++j) h[j] = (_Float16)xs[j];
    whf[(size_t)t * 1024 + q] = h;
  }
  // wnorm: 8 threads per cluster, fp64, shuffle-reduce
  {
    int gid = tid >> 3, j = tid & 7;     // gid 0..31
    int cl = t * 32 + gid - basePad;
    double acc = 0.0;
    if (cl >= 0 && cl < csize) {
      const float* row = wsrc + (size_t)cl * DIM + j * 32;
#pragma unroll
      for (int k = 0; k < 32; ++k) { double x = row[k]; acc += x * x; }
    }
    acc += __shfl_xor(acc, 1, 64);
    acc += __shfl_xor(acc, 2, 64);
    acc += __shfl_xor(acc, 4, 64);
    if (j == 0) {
      float* wn = (float*)(ws + WS_WNORM);
      wn[t * 32 + gid] = (cl >= 0 && cl < csize) ? (float)acc : __builtin_inff();
    }
  }
  if (t == 0 && tid == 0) *(int*)(ws + WS_FLAGCNT) = 0;
}

// -------- main: barrier-free, W-frags streamed global->reg, A/B double buffer --
__global__ __launch_bounds__(128, 2) void argmin_kernel(
    const float* __restrict__ E, const float* __restrict__ w0, const float* __restrict__ w1,
    const float* __restrict__ w2, float* __restrict__ out, unsigned char* __restrict__ ws) {
  const int tid   = threadIdx.x;
  const int lane  = tid & 63;
  const int wave  = tid >> 6;    // 0..1
  const int col   = lane & 31;   // token within 32-tile
  const int khalf = lane >> 5;   // 0/1 (k sub-block / C-row offset)
  const int tokbase = blockIdx.x * 64 + wave * 32;

  // E fragments (B-operand): lane holds E[tok=col][k = s*16 + khalf*8 + j]
  half8 eh[16];
  {
    const float* ep = E + (size_t)(tokbase + col) * DIM;
#pragma unroll
    for (int s = 0; s < 16; ++s) {
      const float4* p = (const float4*)(ep + s * 16 + khalf * 8);
      float4 a = p[0], b = p[1];
      float xs[8] = {a.x, a.y, a.z, a.w, b.x, b.y, b.z, b.w};
      half8 h;
#pragma unroll
      for (int j = 0; j < 8; ++j) h[j] = (_Float16)xs[j];
      eh[s] = h;
    }
  }

  const half8* whf = (const half8*)(ws + WS_WHFRAG);
  const float* wn  = (const float*)(ws + WS_WNORM);

  float v1 = __builtin_inff();
  float v2 = __builtin_inff();
  int   i1 = 0x7fffffff;

  // epilogue macro: d = ||w||^2 - 2S; branch-free online top-2 (no tie-break:
  // exact ties => gap 0 => flagged => refine resolves with exact first-min rule)
#define EPILOGUE(T, ACC)                                                     \
  {                                                                          \
    _Pragma("unroll")                                                        \
    for (int q = 0; q < 4; ++q) {                                            \
      float4 w4 = *(const float4*)(wn + (T) * 32 + q * 8 + khalf * 4);       \
      float wv[4] = {w4.x, w4.y, w4.z, w4.w};                                \
      _Pragma("unroll")                                                      \
      for (int rr = 0; rr < 4; ++rr) {                                       \
        float d = __builtin_fmaf(-2.0f, (ACC)[q * 4 + rr], wv[rr]);          \
        int c = (T) * 32 + rr + 8 * q + 4 * khalf;                           \
        bool lt = d < v1;                                                    \
        float hi = fmaxf(d, v1);                                             \
        v1 = fminf(d, v1);                                                   \
        v2 = fminf(v2, hi);                                                  \
        i1 = lt ? c : i1;                                                    \
      }                                                                      \
    }                                                                        \
  }

#define FINALIZE(LVAL, BASEPAD, WLP)                                         \
  {                                                                          \
    float o1 = __shfl_xor(v1, 32, 64);                                       \
    int   oi = __shfl_xor(i1, 32, 64);                                       \
    float o2 = __shfl_xor(v2, 32, 64);                                       \
    float a1 = fminf(v1, o1);                                                \
    float a2 = fminf(fmaxf(v1, o1), fminf(v2, o2));                          \
    int   b1 = (o1 < v1) ? oi : i1;                                          \
    int li = b1 - (BASEPAD);                                                 \
    if (khalf == 0 && (a2 - a1 < TAU)) {                                     \
      int token = tokbase + col;                                             \
      int pos = atomicAdd((int*)(ws + WS_FLAGCNT), 1);                       \
      if (pos < WS_NFLAGS) ((int*)(ws + WS_FLAGS))[pos] = ((LVAL) << 16) | token; \
    }                                                                        \
    _Pragma("unroll 1")                                                      \
    for (int r = 0; r < 32; ++r) {                                           \
      int ir = __shfl(li, r, 64);                                            \
      const f32x4* src = (const f32x4*)((WLP) + (size_t)ir * DIM);           \
      f32x4* dst = (f32x4*)(out + ((size_t)((LVAL) * N_TOK + tokbase + r)) * DIM); \
      __builtin_nontemporal_store(src[lane], &dst[lane]);                    \
    }                                                                        \
    v1 = __builtin_inff(); v2 = __builtin_inff(); i1 = 0x7fffffff;           \
  }

  // named A/B register double-buffer of W fragments (2 tiles in flight;
  // compiler emits counted vmcnt so next-tile loads stay in flight under MFMA)
  half8 wA[16], wB[16];
#pragma unroll
  for (int s = 0; s < 16; ++s) wA[s] = whf[s * 64 + lane];

#pragma unroll 1
  for (int it = 0; it < NT / 2; ++it) {
    const int t0 = 2 * it, t1 = 2 * it + 1;
    // issue loads for t1 into B
#pragma unroll
    for (int s = 0; s < 16; ++s) wB[s] = whf[(size_t)t1 * 1024 + s * 64 + lane];
    // MFMA tile t0 from A
    {
      f32x16 acc = (f32x16){0.f,0.f,0.f,0.f,0.f,0.f,0.f,0.f,0.f,0.f,0.f,0.f,0.f,0.f,0.f,0.f};
#pragma unroll
      for (int s = 0; s < 16; ++s)
        acc = __builtin_amdgcn_mfma_f32_32x32x16_f16(wA[s], eh[s], acc, 0, 0, 0);
      EPILOGUE(t0, acc);
    }
    if (t0 == 68) FINALIZE(0, 0, w0);
    if (t0 == 74) FINALIZE(1, 2208, w1);
    // issue loads for t0+2 into A
    if (it + 1 < NT / 2) {
#pragma unroll
      for (int s = 0; s < 16; ++s) wA[s] = whf[(size_t)(t0 + 2) * 1024 + s * 64 + lane];
    }
    // MFMA tile t1 from B
    {
      f32x16 acc = (f32x16){0.f,0.f,0.f,0.f,0.f,0.f,0.f,0.f,0.f,0.f,0.f,0.f,0.f,0.f,0.f,0.f};
#pragma unroll
      for (int s = 0; s < 16; ++s)
        acc = __builtin_amdgcn_mfma_f32_32x32x16_f16(wB[s], eh[s], acc, 0, 0, 0);
      EPILOGUE(t1, acc);
    }
    if (t1 == 75) FINALIZE(2, 2400, w2);
  }
#undef EPILOGUE
#undef FINALIZE
}

// ------- refine: exact fp64 rescan, 16-lane cluster groups, coalesced --------
__global__ __launch_bounds__(256) void refine_kernel(
    const float* __restrict__ E, const float* __restrict__ w0,
    const float* __restrict__ w1, const float* __restrict__ w2,
    float* __restrict__ out, unsigned char* __restrict__ ws) {
  __shared__ float esh[DIM];
  __shared__ double wbv[4];
  __shared__ int    wbi[4];
  __shared__ int    sbi;
  const int tid  = threadIdx.x;
  const int lane = tid & 63;
  const int wave = tid >> 6;
  const int g    = tid >> 4;    // 0..15 cluster group
  const int sl   = tid & 15;    // sub-lane within group
  int cnt = *(const int*)(ws + WS_FLAGCNT);
  if (cnt > WS_NFLAGS) cnt = WS_NFLAGS;
  const int* flags = (const int*)(ws + WS_FLAGS);
  for (int f = blockIdx.x; f < cnt; f += gridDim.x) {
    int lin = flags[f];
    int L = lin >> 16, tok = lin & 0xffff;
    const float* WL; int csize;
    if (L == 0)      { WL = w0; csize = 2197; }
    else if (L == 1) { WL = w1; csize = 169; }
    else             { WL = w2; csize = 13; }
    __syncthreads();                         // protect esh/wbv reuse
    esh[tid] = E[(size_t)tok * DIM + tid];   // tid < 256 == DIM
    __syncthreads();
    double best = 1e300; int bi = 0x7fffffff;
    const float4* er = (const float4*)esh;
    for (int c = g; c < csize; c += 16) {
      const float4* row = (const float4*)(WL + (size_t)c * DIM);
      double s0 = 0.0, s1 = 0.0, s2 = 0.0, s3 = 0.0;
#pragma unroll
      for (int p = 0; p < 4; ++p) {
        float4 wv = row[p * 16 + sl];
        float4 ev = er [p * 16 + sl];
        double d0 = (double)wv.x - (double)ev.x;
        double d1 = (double)wv.y - (double)ev.y;
        double d2 = (double)wv.z - (double)ev.z;
        double d3 = (double)wv.w - (double)ev.w;
        s0 += d0 * d0; s1 += d1 * d1; s2 += d2 * d2; s3 += d3 * d3;
      }
      double s = (s0 + s1) + (s2 + s3);
      s += __shfl_xor(s, 1, 64);
      s += __shfl_xor(s, 2, 64);
      s += __shfl_xor(s, 4, 64);
      s += __shfl_xor(s, 8, 64);
      if (s < best || (s == best && c < bi)) { best = s; bi = c; }
    }
    // merge 4 groups within the wave
    {
      double ob = __shfl_xor(best, 16, 64); int oi = __shfl_xor(bi, 16, 64);
      if (ob < best || (ob == best && oi < bi)) { best = ob; bi = oi; }
      ob = __shfl_xor(best, 32, 64); oi = __shfl_xor(bi, 32, 64);
      if (ob < best || (ob == best && oi < bi)) { best = ob; bi = oi; }
    }
    if (lane == 0) { wbv[wave] = best; wbi[wave] = bi; }
    __syncthreads();
    if (tid == 0) {
      double b = wbv[0]; int x = wbi[0];
#pragma unroll
      for (int w = 1; w < 4; ++w)
        if (wbv[w] < b || (wbv[w] == b && wbi[w] < x)) { b = wbv[w]; x = wbi[w]; }
      sbi = x;
    }
    __syncthreads();
    int bidx = sbi;
    out[((size_t)(L * N_TOK + tok)) * DIM + tid] = WL[(size_t)bidx * DIM + tid];
  }
}

extern "C" void kernel_launch(void* const* d_in, const int* in_sizes, int n_in,
                              void* d_out, int out_size, void* d_ws, size_t ws_size,
                              hipStream_t stream) {
  const float* E  = (const float*)d_in[0];
  const float* w0 = (const float*)d_in[1];
  const float* w1 = (const float*)d_in[2];
  const float* w2 = (const float*)d_in[3];
  float* out = (float*)d_out;
  unsigned char* ws = (unsigned char*)d_ws;

  hipLaunchKernelGGL(prep_kernel,   dim3(NT),   dim3(256), 0, stream, w0, w1, w2, ws);
  hipLaunchKernelGGL(argmin_kernel, dim3(1024), dim3(128), 0, stream, E, w0, w1, w2, out, ws);
  hipLaunchKernelGGL(refine_kernel, dim3(1024), dim3(256), 0, stream, E, w0, w1, w2, out, ws);
}